// Round 4
// baseline (1106.046 us; speedup 1.0000x reference)
//
#include <hip/hip_runtime.h>
#include <stdint.h>

#define B_DIM 512
#define I_DIM 128
#define H_DIM 128
#define G_DIM 384
#define STEPS 511   // reference scans t = 0..T-2

typedef __attribute__((ext_vector_type(8))) short bf16x8;
typedef __attribute__((ext_vector_type(4))) float f32x4;
typedef _Float16 half2_t __attribute__((ext_vector_type(2)));

__device__ __forceinline__ unsigned bf16rne(float f) {
  unsigned u = __float_as_uint(f);
  return (u + 0x7fffu + ((u >> 16) & 1u)) >> 16;
}
__device__ __forceinline__ short bf16s(float f) { return (short)bf16rne(f); }

__device__ __forceinline__ float fdot2(half2_t a, half2_t b, float c) {
#if __has_builtin(__builtin_amdgcn_fdot2)
  return __builtin_amdgcn_fdot2(a, b, c, false);
#else
  return fmaf((float)a.x, (float)b.x, fmaf((float)a.y, (float)b.y, c));
#endif
}

// Barrier that drains ONLY LDS ops: global prefetches stay in flight across
// it (the compiler's __syncthreads would emit s_waitcnt vmcnt(0) and expose
// L3 latency every step).
#define BAR_LDS() asm volatile("s_waitcnt lgkmcnt(0)\n\ts_barrier" ::: "memory")

// ---------------------------------------------------------------------------
// Kernel A (MFMA): xp[row][g] = x[row][:] . Wih[g][:] + bih[g]
// One block = 128 rows x ALL 384 gate-cols (x tile staged once). 512 thr =
// 8 waves; wave (mh=w&1, nh=w>>1): 4 M-frags x 6 N-frags x 4 K-steps.
// A staged bf16 in LDS, XOR swizzle byte^=((row&7)<<4) both sides.
// ---------------------------------------------------------------------------
__global__ __launch_bounds__(512, 2) void k_xproj(
    const float* __restrict__ xch, const float* __restrict__ Wih,
    const float* __restrict__ bih, float* __restrict__ xp) {
  __shared__ __align__(16) char As[128 * 256];  // 32 KB bf16 A tile
  const int tid = threadIdx.x;
  const int lane = tid & 63;
  const int wave = tid >> 6;
  const int mh = wave & 1, nh = wave >> 1;   // nh in [0,4): 96-col quarter
  const int l15 = lane & 15, l4 = lane >> 4;

  // ---- stage A tile: global fp32 (coalesced float4) -> bf16 LDS ----
  const float4* xs = (const float4*)(xch + (size_t)blockIdx.x * 128 * I_DIM);
#pragma unroll
  for (int q = 0; q < 8; ++q) {
    const int fi = tid + 512 * q;           // float4 index in 128x128 tile
    const int row = fi >> 5, kq = fi & 31;
    const float4 v = xs[fi];
    uint2 p;
    p.x = bf16rne(v.x) | (bf16rne(v.y) << 16);
    p.y = bf16rne(v.z) | (bf16rne(v.w) << 16);
    *(uint2*)(As + (row << 8) + ((kq << 3) ^ ((row & 7) << 4))) = p;
  }

  // ---- B fragments (Wih) -> registers, loop-invariant ----
  bf16x8 bf[6][4];
  float bv[6];
#pragma unroll
  for (int nf = 0; nf < 6; ++nf) {
    const int col = nh * 96 + nf * 16 + l15;
    bv[nf] = bih[col];
#pragma unroll
    for (int ks = 0; ks < 4; ++ks) {
      const float* wr = Wih + (size_t)col * I_DIM + ks * 32 + l4 * 8;
      const float4 wa = *(const float4*)wr;
      const float4 wb = *(const float4*)(wr + 4);
      bf16x8 b;
      b[0] = bf16s(wa.x); b[1] = bf16s(wa.y); b[2] = bf16s(wa.z); b[3] = bf16s(wa.w);
      b[4] = bf16s(wb.x); b[5] = bf16s(wb.y); b[6] = bf16s(wb.z); b[7] = bf16s(wb.w);
      bf[nf][ks] = b;
    }
  }
  __syncthreads();

  f32x4 acc[4][6];
#pragma unroll
  for (int m = 0; m < 4; ++m)
#pragma unroll
    for (int nf = 0; nf < 6; ++nf) acc[m][nf] = (f32x4){0.f, 0.f, 0.f, 0.f};

#pragma unroll
  for (int ks = 0; ks < 4; ++ks) {
#pragma unroll
    for (int m = 0; m < 4; ++m) {
      const int arow = mh * 64 + m * 16 + l15;
      const int kbyte = ks * 64 + l4 * 16;
      const bf16x8 a =
          *(const bf16x8*)(As + (arow << 8) + (kbyte ^ ((arow & 7) << 4)));
#pragma unroll
      for (int nf = 0; nf < 6; ++nf)
        acc[m][nf] =
            __builtin_amdgcn_mfma_f32_16x16x32_bf16(a, bf[nf][ks], acc[m][nf], 0, 0, 0);
    }
  }

  // ---- epilogue: D[row=4*(l>>4)+r][col=l&15] ----
#pragma unroll
  for (int m = 0; m < 4; ++m) {
    const size_t row0 = (size_t)blockIdx.x * 128 + mh * 64 + m * 16 + l4 * 4;
#pragma unroll
    for (int nf = 0; nf < 6; ++nf) {
      const int col = nh * 96 + nf * 16 + l15;
#pragma unroll
      for (int r = 0; r < 4; ++r)
        xp[(row0 + r) * G_DIM + col] = acc[m][nf][r] + bv[nf];
    }
  }
}

// ---------------------------------------------------------------------------
// Kernel B: GRU recurrence. 512 blocks x 1 row, 128 threads (2 waves).
// Wave = K-half (64 each). Thread owns 6 gates {lane+64*gi}, W f16 in
// registers (192 VGPR). h f16-packed in 256B LDS (wave-uniform b128
// broadcast reads). h_old in a register (thread j == unit j). xp read
// straight to registers. LDS-only barriers; vmcnt never drained in loop.
// ---------------------------------------------------------------------------
__global__ __launch_bounds__(128, 2) void k_rec(
    const float* __restrict__ xp, const float* __restrict__ gt,
    const float* __restrict__ Whh, const float* __restrict__ bhh,
    const float* __restrict__ Wdec, const float* __restrict__ bdec,
    float* __restrict__ ws_h, float* __restrict__ nll_part,
    int t0, int t1, int first) {
  __shared__ float pp[2][G_DIM];                   // K-half partials
  __shared__ float p_lds[H_DIM];                   // decode partials
  __shared__ __align__(16) unsigned h2u[H_DIM / 2];  // h packed f16x2

  const int tid = threadIdx.x;
  const int lane = tid & 63;
  const int w = tid >> 6;          // K-half
  const int j = tid;               // GRU unit (phase B identity)
  const int row = blockIdx.x;

  // ---- one-time: W_hh K-half slice -> f16 packed registers ----
  half2_t wg[6][32];
#pragma unroll
  for (int gi = 0; gi < 6; ++gi) {
    const float4* wp =
        (const float4*)(Whh + (size_t)(gi * 64 + lane) * H_DIM + w * 64);
#pragma unroll
    for (int c = 0; c < 16; ++c) {
      const float4 v = wp[c];
      half2_t a, b;
      a.x = (_Float16)v.x; a.y = (_Float16)v.y;
      b.x = (_Float16)v.z; b.y = (_Float16)v.w;
      wg[gi][2 * c] = a;
      wg[gi][2 * c + 1] = b;
    }
  }
  const float bhr = bhh[j], bhz = bhh[128 + j], bhn = bhh[256 + j];
  const float wdj = Wdec[j];
  const float bd0 = bdec[0];

  float h_old = first ? 0.f : ws_h[(size_t)row * H_DIM + j];
  {
    const float hb = __shfl_xor(h_old, 1);
    if (!(tid & 1)) {
      half2_t hp; hp.x = (_Float16)h_old; hp.y = (_Float16)hb;
      h2u[tid >> 1] = __builtin_bit_cast(unsigned, hp);
    }
  }
  __syncthreads();

  float nll0 = 0.f, g_cur = 0.f, g_next = 0.f;
  const float4* hv4 = (const float4*)h2u;

#pragma unroll 1
  for (int s = t0; s < t1; ++s) {
    // this step's xp values + next step's gt: issued early, consumed late;
    // they stay in flight across BAR_LDS (no vmcnt drain).
    const size_t base = ((size_t)(s - t0) * B_DIM + row) * G_DIM;
    const float xr = xp[base + j];
    const float xz = xp[base + 128 + j];
    const float xn = xp[base + 256 + j];
    if (tid == 0) g_next = gt[(size_t)(s + 1) * B_DIM + row];

    // decode + NLL for step s-1 on wave 0 (p_lds stable until phase B)
    if (s > t0 && tid < 64) {
      float v = p_lds[tid] + p_lds[tid + 64];
#pragma unroll
      for (int off = 32; off; off >>= 1) v += __shfl_down(v, off);
      if (tid == 0) {
        const float C = 1.f / (1.f + __expf(-(v + bd0)));
        nll0 -= g_cur * __logf(C + 1e-4f) +
                (1.f - g_cur) * __logf(1.f - C + 1e-4f);
      }
    }

    // ---- phase A: 192 dot2 over this K-half, 6 independent chains ----
    float a0 = 0.f, a1 = 0.f, a2 = 0.f, a3 = 0.f, a4 = 0.f, a5 = 0.f;
#pragma unroll
    for (int c = 0; c < 8; ++c) {
      const float4 hq = hv4[w * 8 + c];  // wave-uniform -> broadcast
      const half2_t h0 = __builtin_bit_cast(half2_t, hq.x);
      const half2_t h1 = __builtin_bit_cast(half2_t, hq.y);
      const half2_t h2 = __builtin_bit_cast(half2_t, hq.z);
      const half2_t h3 = __builtin_bit_cast(half2_t, hq.w);
      a0 = fdot2(h0, wg[0][4 * c], a0);     a0 = fdot2(h1, wg[0][4 * c + 1], a0);
      a0 = fdot2(h2, wg[0][4 * c + 2], a0); a0 = fdot2(h3, wg[0][4 * c + 3], a0);
      a1 = fdot2(h0, wg[1][4 * c], a1);     a1 = fdot2(h1, wg[1][4 * c + 1], a1);
      a1 = fdot2(h2, wg[1][4 * c + 2], a1); a1 = fdot2(h3, wg[1][4 * c + 3], a1);
      a2 = fdot2(h0, wg[2][4 * c], a2);     a2 = fdot2(h1, wg[2][4 * c + 1], a2);
      a2 = fdot2(h2, wg[2][4 * c + 2], a2); a2 = fdot2(h3, wg[2][4 * c + 3], a2);
      a3 = fdot2(h0, wg[3][4 * c], a3);     a3 = fdot2(h1, wg[3][4 * c + 1], a3);
      a3 = fdot2(h2, wg[3][4 * c + 2], a3); a3 = fdot2(h3, wg[3][4 * c + 3], a3);
      a4 = fdot2(h0, wg[4][4 * c], a4);     a4 = fdot2(h1, wg[4][4 * c + 1], a4);
      a4 = fdot2(h2, wg[4][4 * c + 2], a4); a4 = fdot2(h3, wg[4][4 * c + 3], a4);
      a5 = fdot2(h0, wg[5][4 * c], a5);     a5 = fdot2(h1, wg[5][4 * c + 1], a5);
      a5 = fdot2(h2, wg[5][4 * c + 2], a5); a5 = fdot2(h3, wg[5][4 * c + 3], a5);
    }
    pp[w][lane]       = a0;
    pp[w][64 + lane]  = a1;
    pp[w][128 + lane] = a2;
    pp[w][192 + lane] = a3;
    pp[w][256 + lane] = a4;
    pp[w][320 + lane] = a5;
    BAR_LDS();  // barrier 1: partials published; h2u reads done

    // ---- phase B: all 128 threads, one GRU unit each ----
    {
      const float rp = pp[0][j] + pp[1][j] + xr + bhr;
      const float zp = pp[0][128 + j] + pp[1][128 + j] + xz + bhz;
      const float hn = pp[0][256 + j] + pp[1][256 + j] + bhn;
      const float r_ = 1.f / (1.f + __expf(-rp));
      const float z_ = 1.f / (1.f + __expf(-zp));
      const float e2 = __expf(2.f * (xn + r_ * hn));
      const float n_ = 1.f - 2.f / (e2 + 1.f);
      const float hnew = (1.f - z_) * n_ + z_ * h_old;
      h_old = hnew;
      p_lds[j] = hnew * wdj;
      const float hb = __shfl_xor(hnew, 1);
      if (!(tid & 1)) {
        half2_t hp; hp.x = (_Float16)hnew; hp.y = (_Float16)hb;
        h2u[tid >> 1] = __builtin_bit_cast(unsigned, hp);
      }
    }
    BAR_LDS();  // barrier 2: h ready for next step
    g_cur = g_next;
  }

  // trailing decode for s = t1-1 (g_cur = gt[t1])
  if (tid < 64) {
    float v = p_lds[tid] + p_lds[tid + 64];
#pragma unroll
    for (int off = 32; off; off >>= 1) v += __shfl_down(v, off);
    if (tid == 0) {
      const float C = 1.f / (1.f + __expf(-(v + bd0)));
      nll0 -= g_cur * __logf(C + 1e-4f) +
              (1.f - g_cur) * __logf(1.f - C + 1e-4f);
    }
  }

  ws_h[(size_t)row * H_DIM + j] = h_old;
  if (tid == 0)
    nll_part[row] = first ? nll0 : (nll_part[row] + nll0);
}

// ---------------------------------------------------------------------------
__global__ __launch_bounds__(512) void k_fin(const float* __restrict__ nll_part,
                                             float* __restrict__ out) {
  __shared__ float red[8];
  const int tid = threadIdx.x;
  float v = nll_part[tid];
#pragma unroll
  for (int off = 32; off; off >>= 1) v += __shfl_down(v, off);
  if ((tid & 63) == 0) red[tid >> 6] = v;
  __syncthreads();
  if (tid == 0) {
    float s = 0.f;
#pragma unroll
    for (int i = 0; i < 8; ++i) s += red[i];
    out[0] = s * (1.f / (512.f * 512.f));
  }
}

// ---------------------------------------------------------------------------
extern "C" void kernel_launch(void* const* d_in, const int* in_sizes, int n_in,
                              void* d_out, int out_size, void* d_ws,
                              size_t ws_size, hipStream_t stream) {
  const float* x    = (const float*)d_in[0];
  const float* gt   = (const float*)d_in[1];
  const float* Wih  = (const float*)d_in[2];
  const float* Whh  = (const float*)d_in[3];
  const float* bih  = (const float*)d_in[4];
  const float* bhh  = (const float*)d_in[5];
  const float* Wdec = (const float*)d_in[6];
  const float* bdec = (const float*)d_in[7];

  // ws layout: [0,2KB) nll_part[512]; [4KB,260KB) h state; then xp chunk
  float* nll_part = (float*)d_ws;
  float* ws_h = (float*)((char*)d_ws + 4096);
  const size_t xp_off = 4096 + (size_t)B_DIM * H_DIM * 4;  // 266240
  float* xp = (float*)((char*)d_ws + xp_off);

  const size_t chunk_bytes = (size_t)B_DIM * G_DIM * 4;  // per timestep
  size_t avail = ws_size > xp_off ? ws_size - xp_off : 0;
  int Tc = (int)(avail / chunk_bytes);
  if (Tc > 128) Tc = 128;      // xp chunk <=96 MB still L3-resident
  if (Tc < 1) Tc = 1;

  for (int t0 = 0; t0 < STEPS; t0 += Tc) {
    int t1 = t0 + Tc;
    if (t1 > STEPS) t1 = STEPS;
    const int nt = t1 - t0;
    k_xproj<<<dim3(nt * 4), dim3(512), 0, stream>>>(
        x + (size_t)t0 * B_DIM * I_DIM, Wih, bih, xp);
    k_rec<<<dim3(512), dim3(128), 0, stream>>>(
        xp, gt, Whh, bhh, Wdec, bdec, ws_h, nll_part, t0, t1, t0 == 0 ? 1 : 0);
  }
  k_fin<<<dim3(1), dim3(512), 0, stream>>>(nll_part, (float*)d_out);
}

// Round 5
// 988.622 us; speedup vs baseline: 1.1188x; 1.1188x over previous
//
#include <hip/hip_runtime.h>
#include <stdint.h>

#define B_DIM 512
#define I_DIM 128
#define H_DIM 128
#define G_DIM 384
#define STEPS 511   // reference scans t = 0..T-2

typedef __attribute__((ext_vector_type(8))) short bf16x8;
typedef __attribute__((ext_vector_type(4))) float f32x4;
typedef _Float16 half2_t __attribute__((ext_vector_type(2)));

__device__ __forceinline__ unsigned bf16rne(float f) {
  unsigned u = __float_as_uint(f);
  return (u + 0x7fffu + ((u >> 16) & 1u)) >> 16;
}
__device__ __forceinline__ short bf16s(float f) { return (short)bf16rne(f); }

// Barrier draining ONLY LDS ops; global prefetches stay in flight across it.
#define BAR_LDS() asm volatile("s_waitcnt lgkmcnt(0)\n\ts_barrier" ::: "memory")

// ---------------------------------------------------------------------------
// Kernel A (MFMA): xp[row][g] = x[row][:] . Wih[g][:] + bih[g] (+ bhh[g] for
// the r,z gate thirds — folded here so k_rec's phase B skips those adds).
// Output fp16 (halves traffic; 64-step chunk = 25 MB -> L3-resident).
// One block = 128 rows x all 384 cols; A staged bf16 in LDS (XOR swizzle
// both sides); B frags register-resident.
// ---------------------------------------------------------------------------
__global__ __launch_bounds__(512, 2) void k_xproj(
    const float* __restrict__ xch, const float* __restrict__ Wih,
    const float* __restrict__ bih, const float* __restrict__ bhh,
    _Float16* __restrict__ xp) {
  __shared__ __align__(16) char As[128 * 256];  // 32 KB bf16 A tile
  const int tid = threadIdx.x;
  const int lane = tid & 63;
  const int wave = tid >> 6;
  const int mh = wave & 1, nh = wave >> 1;   // nh in [0,4): 96-col quarter
  const int l15 = lane & 15, l4 = lane >> 4;

  const float4* xs = (const float4*)(xch + (size_t)blockIdx.x * 128 * I_DIM);
#pragma unroll
  for (int q = 0; q < 8; ++q) {
    const int fi = tid + 512 * q;
    const int row = fi >> 5, kq = fi & 31;
    const float4 v = xs[fi];
    uint2 p;
    p.x = bf16rne(v.x) | (bf16rne(v.y) << 16);
    p.y = bf16rne(v.z) | (bf16rne(v.w) << 16);
    *(uint2*)(As + (row << 8) + ((kq << 3) ^ ((row & 7) << 4))) = p;
  }

  bf16x8 bf[6][4];
  float bv[6];
#pragma unroll
  for (int nf = 0; nf < 6; ++nf) {
    const int col = nh * 96 + nf * 16 + l15;
    bv[nf] = bih[col] + (col < 256 ? bhh[col] : 0.f);  // fold bhh for r,z
#pragma unroll
    for (int ks = 0; ks < 4; ++ks) {
      const float* wr = Wih + (size_t)col * I_DIM + ks * 32 + l4 * 8;
      const float4 wa = *(const float4*)wr;
      const float4 wb = *(const float4*)(wr + 4);
      bf16x8 b;
      b[0] = bf16s(wa.x); b[1] = bf16s(wa.y); b[2] = bf16s(wa.z); b[3] = bf16s(wa.w);
      b[4] = bf16s(wb.x); b[5] = bf16s(wb.y); b[6] = bf16s(wb.z); b[7] = bf16s(wb.w);
      bf[nf][ks] = b;
    }
  }
  __syncthreads();

  f32x4 acc[4][6];
#pragma unroll
  for (int m = 0; m < 4; ++m)
#pragma unroll
    for (int nf = 0; nf < 6; ++nf) acc[m][nf] = (f32x4){0.f, 0.f, 0.f, 0.f};

#pragma unroll
  for (int ks = 0; ks < 4; ++ks) {
#pragma unroll
    for (int m = 0; m < 4; ++m) {
      const int arow = mh * 64 + m * 16 + l15;
      const int kbyte = ks * 64 + l4 * 16;
      const bf16x8 a =
          *(const bf16x8*)(As + (arow << 8) + (kbyte ^ ((arow & 7) << 4)));
#pragma unroll
      for (int nf = 0; nf < 6; ++nf)
        acc[m][nf] =
            __builtin_amdgcn_mfma_f32_16x16x32_bf16(a, bf[nf][ks], acc[m][nf], 0, 0, 0);
    }
  }

#pragma unroll
  for (int m = 0; m < 4; ++m) {
    const size_t row0 = (size_t)blockIdx.x * 128 + mh * 64 + m * 16 + l4 * 4;
#pragma unroll
    for (int nf = 0; nf < 6; ++nf) {
      const int col = nh * 96 + nf * 16 + l15;
#pragma unroll
      for (int r = 0; r < 4; ++r)
        xp[(row0 + r) * G_DIM + col] = (_Float16)(acc[m][nf][r] + bv[nf]);
    }
  }
}

// ---------------------------------------------------------------------------
// Kernel B: GRU recurrence. 512 blocks x 1 row, 256 threads (4 waves),
// 2 blocks/CU (8 waves/CU). Thread = (j = tid&127, split = tid>>7).
// W_hh f16-packed in 96 VGPRs (w[3][32] half2 — fits, NO spill).
// Matvec via v_pk_fma_f16 (native half2 arithmetic, 2 MAC/lane/cyc).
// h f16-packed in 256B LDS, wave-uniform uint4 broadcast reads.
// xp prefetched one full step ahead into registers. LDS-only barriers.
// ---------------------------------------------------------------------------
__global__ __launch_bounds__(256, 2) void k_rec(
    const _Float16* __restrict__ xp, const float* __restrict__ gt,
    const float* __restrict__ Whh, const float* __restrict__ bhh,
    const float* __restrict__ Wdec, const float* __restrict__ bdec,
    float* __restrict__ ws_h, float* __restrict__ nll_part,
    int t0, int t1, int first) {
  __shared__ unsigned pp[3][2][H_DIM];             // f16x2 partials
  __shared__ __align__(16) unsigned h2u[H_DIM / 2];
  __shared__ float red_s[2];

  const int tid = threadIdx.x;
  const int j = tid & 127;
  const int split = tid >> 7;   // wave-uniform (waves 0,1 = split 0)
  const int row = blockIdx.x;

  // ---- one-time: W_hh K-half slice -> 96 VGPRs of packed f16 ----
  half2_t w0[32], w1[32], w2[32];
  {
    const float4* p0 = (const float4*)(Whh + (size_t)j * H_DIM + split * 64);
    const float4* p1 = (const float4*)(Whh + (size_t)(128 + j) * H_DIM + split * 64);
    const float4* p2 = (const float4*)(Whh + (size_t)(256 + j) * H_DIM + split * 64);
#pragma unroll
    for (int c = 0; c < 16; ++c) {
      float4 v;
      v = p0[c];
      w0[2 * c] = (half2_t){(_Float16)v.x, (_Float16)v.y};
      w0[2 * c + 1] = (half2_t){(_Float16)v.z, (_Float16)v.w};
      v = p1[c];
      w1[2 * c] = (half2_t){(_Float16)v.x, (_Float16)v.y};
      w1[2 * c + 1] = (half2_t){(_Float16)v.z, (_Float16)v.w};
      v = p2[c];
      w2[2 * c] = (half2_t){(_Float16)v.x, (_Float16)v.y};
      w2[2 * c + 1] = (half2_t){(_Float16)v.z, (_Float16)v.w};
    }
  }
  const float bhn = bhh[256 + j];   // n-gate bias NOT foldable into xp
  const float wdj = Wdec[j];
  const float bd0 = bdec[0];

  float h_old = 0.f;
  if (tid < 128) {
    h_old = first ? 0.f : ws_h[(size_t)row * H_DIM + j];
    const float hb = __shfl_xor(h_old, 1);
    if (!(j & 1)) {
      half2_t hp; hp.x = (_Float16)h_old; hp.y = (_Float16)hb;
      h2u[j >> 1] = __builtin_bit_cast(unsigned, hp);
    }
  }
  __syncthreads();

  // xp for the first step, prefetched now
  _Float16 xr_c = (_Float16)0.f, xz_c = (_Float16)0.f, xn_c = (_Float16)0.f;
  if (tid < 128) {
    const size_t b0 = (size_t)row * G_DIM;
    xr_c = xp[b0 + j];
    xz_c = xp[b0 + 128 + j];
    xn_c = xp[b0 + 256 + j];
  }
  float nll0 = 0.f, g_cur = 0.f, g_next = 0.f;
  const uint4* hq4 = (const uint4*)h2u;

#pragma unroll 1
  for (int s = t0; s < t1; ++s) {
    // prefetch NEXT step's xp (full step of latency slack) and gt
    _Float16 xr_n = (_Float16)0.f, xz_n = (_Float16)0.f, xn_n = (_Float16)0.f;
    if (s + 1 < t1 && tid < 128) {
      const size_t b = ((size_t)(s + 1 - t0) * B_DIM + row) * G_DIM;
      xr_n = xp[b + j];
      xz_n = xp[b + 128 + j];
      xn_n = xp[b + 256 + j];
    }
    if (tid == 128) g_next = gt[(size_t)(s + 1) * B_DIM + row];

    // finalize NLL for step s-1 (red_s stable between bar2(s-1) and bar1(s))
    if (tid == 128 && s > t0) {
      const float v = red_s[0] + red_s[1];
      const float C = 1.f / (1.f + __expf(-(v + bd0)));
      nll0 -= g_cur * __logf(C + 1e-4f) +
              (1.f - g_cur) * __logf(1.f - C + 1e-4f);
    }

    // ---- phase A: 96 pk_fma over this K-half, 3 chains ----
    half2_t a0 = (half2_t){0, 0}, a1 = (half2_t){0, 0}, a2 = (half2_t){0, 0};
#pragma unroll
    for (int c = 0; c < 8; ++c) {
      const uint4 hq = hq4[split * 8 + c];  // wave-uniform -> LDS broadcast
      const half2_t h0 = __builtin_bit_cast(half2_t, hq.x);
      const half2_t h1 = __builtin_bit_cast(half2_t, hq.y);
      const half2_t h2 = __builtin_bit_cast(half2_t, hq.z);
      const half2_t h3 = __builtin_bit_cast(half2_t, hq.w);
      a0 = h0 * w0[4 * c] + a0;     a1 = h0 * w1[4 * c] + a1;     a2 = h0 * w2[4 * c] + a2;
      a0 = h1 * w0[4 * c + 1] + a0; a1 = h1 * w1[4 * c + 1] + a1; a2 = h1 * w2[4 * c + 1] + a2;
      a0 = h2 * w0[4 * c + 2] + a0; a1 = h2 * w1[4 * c + 2] + a1; a2 = h2 * w2[4 * c + 2] + a2;
      a0 = h3 * w0[4 * c + 3] + a0; a1 = h3 * w1[4 * c + 3] + a1; a2 = h3 * w2[4 * c + 3] + a2;
    }
    pp[0][split][j] = __builtin_bit_cast(unsigned, a0);
    pp[1][split][j] = __builtin_bit_cast(unsigned, a1);
    pp[2][split][j] = __builtin_bit_cast(unsigned, a2);
    BAR_LDS();  // barrier 1: partials published; h2u reads done

    // ---- phase B: 128 threads (waves 0,1), one GRU unit each ----
    if (tid < 128) {
      const half2_t r0 = __builtin_bit_cast(half2_t, pp[0][0][j]);
      const half2_t r1 = __builtin_bit_cast(half2_t, pp[0][1][j]);
      const half2_t z0 = __builtin_bit_cast(half2_t, pp[1][0][j]);
      const half2_t z1 = __builtin_bit_cast(half2_t, pp[1][1][j]);
      const half2_t n0 = __builtin_bit_cast(half2_t, pp[2][0][j]);
      const half2_t n1 = __builtin_bit_cast(half2_t, pp[2][1][j]);
      const float rp = (float)r0.x + (float)r0.y + (float)r1.x + (float)r1.y +
                       (float)xr_c;  // bhh_r folded into xp
      const float zp = (float)z0.x + (float)z0.y + (float)z1.x + (float)z1.y +
                       (float)xz_c;
      const float hn = (float)n0.x + (float)n0.y + (float)n1.x + (float)n1.y +
                       bhn;
      const float r_ = 1.f / (1.f + __expf(-rp));
      const float z_ = 1.f / (1.f + __expf(-zp));
      const float e2 = __expf(2.f * ((float)xn_c + r_ * hn));
      const float n_ = 1.f - 2.f / (e2 + 1.f);
      const float hnew = (1.f - z_) * n_ + z_ * h_old;
      h_old = hnew;
      // decode partial reduce (per wave, j 0-63 / 64-127)
      float pv = hnew * wdj;
#pragma unroll
      for (int off = 32; off; off >>= 1) pv += __shfl_down(pv, off);
      if ((tid & 63) == 0) red_s[tid >> 6] = pv;
      // republish h as packed f16
      const float hb = __shfl_xor(hnew, 1);
      if (!(j & 1)) {
        half2_t hp; hp.x = (_Float16)hnew; hp.y = (_Float16)hb;
        h2u[j >> 1] = __builtin_bit_cast(unsigned, hp);
      }
    }
    BAR_LDS();  // barrier 2: h + red_s ready
    xr_c = xr_n; xz_c = xz_n; xn_c = xn_n;
    g_cur = g_next;
  }

  // trailing NLL for s = t1-1 (g_cur = gt[t1])
  if (tid == 128) {
    const float v = red_s[0] + red_s[1];
    const float C = 1.f / (1.f + __expf(-(v + bd0)));
    nll0 -= g_cur * __logf(C + 1e-4f) +
            (1.f - g_cur) * __logf(1.f - C + 1e-4f);
    nll_part[row] = first ? nll0 : (nll_part[row] + nll0);
  }
  if (tid < 128) ws_h[(size_t)row * H_DIM + j] = h_old;
}

// ---------------------------------------------------------------------------
__global__ __launch_bounds__(512) void k_fin(const float* __restrict__ nll_part,
                                             float* __restrict__ out) {
  __shared__ float red[8];
  const int tid = threadIdx.x;
  float v = nll_part[tid];
#pragma unroll
  for (int off = 32; off; off >>= 1) v += __shfl_down(v, off);
  if ((tid & 63) == 0) red[tid >> 6] = v;
  __syncthreads();
  if (tid == 0) {
    float s = 0.f;
#pragma unroll
    for (int i = 0; i < 8; ++i) s += red[i];
    out[0] = s * (1.f / (512.f * 512.f));
  }
}

// ---------------------------------------------------------------------------
extern "C" void kernel_launch(void* const* d_in, const int* in_sizes, int n_in,
                              void* d_out, int out_size, void* d_ws,
                              size_t ws_size, hipStream_t stream) {
  const float* x    = (const float*)d_in[0];
  const float* gt   = (const float*)d_in[1];
  const float* Wih  = (const float*)d_in[2];
  const float* Whh  = (const float*)d_in[3];
  const float* bih  = (const float*)d_in[4];
  const float* bhh  = (const float*)d_in[5];
  const float* Wdec = (const float*)d_in[6];
  const float* bdec = (const float*)d_in[7];

  // ws layout: [0,2KB) nll_part[512]; [4KB,260KB) h state; then xp chunk
  float* nll_part = (float*)d_ws;
  float* ws_h = (float*)((char*)d_ws + 4096);
  const size_t xp_off = 4096 + (size_t)B_DIM * H_DIM * 4;  // 266240
  _Float16* xp = (_Float16*)((char*)d_ws + xp_off);

  const size_t chunk_bytes = (size_t)B_DIM * G_DIM * 2;  // fp16 per timestep
  size_t avail = ws_size > xp_off ? ws_size - xp_off : 0;
  int Tc = (int)(avail / chunk_bytes);
  if (Tc > 64) Tc = 64;        // xp chunk <=25 MB, L3-resident
  if (Tc < 1) Tc = 1;

  for (int t0 = 0; t0 < STEPS; t0 += Tc) {
    int t1 = t0 + Tc;
    if (t1 > STEPS) t1 = STEPS;
    const int nt = t1 - t0;
    k_xproj<<<dim3(nt * 4), dim3(512), 0, stream>>>(
        x + (size_t)t0 * B_DIM * I_DIM, Wih, bih, bhh, xp);
    k_rec<<<dim3(512), dim3(256), 0, stream>>>(
        xp, gt, Whh, bhh, Wdec, bdec, ws_h, nll_part, t0, t1, t0 == 0 ? 1 : 0);
  }
  k_fin<<<dim3(1), dim3(512), 0, stream>>>(nll_part, (float*)d_out);
}

// Round 6
// 885.667 us; speedup vs baseline: 1.2488x; 1.1162x over previous
//
#include <hip/hip_runtime.h>
#include <stdint.h>

#define B_DIM 512
#define I_DIM 128
#define H_DIM 128
#define G_DIM 384
#define STEPS 511   // reference scans t = 0..T-2

typedef __attribute__((ext_vector_type(8))) short bf16x8;
typedef __attribute__((ext_vector_type(4))) float f32x4;
typedef _Float16 half2_t __attribute__((ext_vector_type(2)));

__device__ __forceinline__ unsigned bf16rne(float f) {
  unsigned u = __float_as_uint(f);
  return (u + 0x7fffu + ((u >> 16) & 1u)) >> 16;
}
__device__ __forceinline__ short bf16s(float f) { return (short)bf16rne(f); }

// Barrier draining ONLY LDS ops; global prefetches stay in flight across it.
#define BAR_LDS() asm volatile("s_waitcnt lgkmcnt(0)\n\ts_barrier" ::: "memory")

// ---------------------------------------------------------------------------
// Kernel A (MFMA): xp[row][g] = x[row][:].Wih[g][:] + bih[g] (+bhh[g] folded
// for the r,z thirds). fp16 output. Unchanged from round 5.
// ---------------------------------------------------------------------------
__global__ __launch_bounds__(512, 2) void k_xproj(
    const float* __restrict__ xch, const float* __restrict__ Wih,
    const float* __restrict__ bih, const float* __restrict__ bhh,
    _Float16* __restrict__ xp) {
  __shared__ __align__(16) char As[128 * 256];  // 32 KB bf16 A tile
  const int tid = threadIdx.x;
  const int lane = tid & 63;
  const int wave = tid >> 6;
  const int mh = wave & 1, nh = wave >> 1;
  const int l15 = lane & 15, l4 = lane >> 4;

  const float4* xs = (const float4*)(xch + (size_t)blockIdx.x * 128 * I_DIM);
#pragma unroll
  for (int q = 0; q < 8; ++q) {
    const int fi = tid + 512 * q;
    const int row = fi >> 5, kq = fi & 31;
    const float4 v = xs[fi];
    uint2 p;
    p.x = bf16rne(v.x) | (bf16rne(v.y) << 16);
    p.y = bf16rne(v.z) | (bf16rne(v.w) << 16);
    *(uint2*)(As + (row << 8) + ((kq << 3) ^ ((row & 7) << 4))) = p;
  }

  bf16x8 bf[6][4];
  float bv[6];
#pragma unroll
  for (int nf = 0; nf < 6; ++nf) {
    const int col = nh * 96 + nf * 16 + l15;
    bv[nf] = bih[col] + (col < 256 ? bhh[col] : 0.f);
#pragma unroll
    for (int ks = 0; ks < 4; ++ks) {
      const float* wr = Wih + (size_t)col * I_DIM + ks * 32 + l4 * 8;
      const float4 wa = *(const float4*)wr;
      const float4 wb = *(const float4*)(wr + 4);
      bf16x8 b;
      b[0] = bf16s(wa.x); b[1] = bf16s(wa.y); b[2] = bf16s(wa.z); b[3] = bf16s(wa.w);
      b[4] = bf16s(wb.x); b[5] = bf16s(wb.y); b[6] = bf16s(wb.z); b[7] = bf16s(wb.w);
      bf[nf][ks] = b;
    }
  }
  __syncthreads();

  f32x4 acc[4][6];
#pragma unroll
  for (int m = 0; m < 4; ++m)
#pragma unroll
    for (int nf = 0; nf < 6; ++nf) acc[m][nf] = (f32x4){0.f, 0.f, 0.f, 0.f};

#pragma unroll
  for (int ks = 0; ks < 4; ++ks) {
#pragma unroll
    for (int m = 0; m < 4; ++m) {
      const int arow = mh * 64 + m * 16 + l15;
      const int kbyte = ks * 64 + l4 * 16;
      const bf16x8 a =
          *(const bf16x8*)(As + (arow << 8) + (kbyte ^ ((arow & 7) << 4)));
#pragma unroll
      for (int nf = 0; nf < 6; ++nf)
        acc[m][nf] =
            __builtin_amdgcn_mfma_f32_16x16x32_bf16(a, bf[nf][ks], acc[m][nf], 0, 0, 0);
    }
  }

#pragma unroll
  for (int m = 0; m < 4; ++m) {
    const size_t row0 = (size_t)blockIdx.x * 128 + mh * 64 + m * 16 + l4 * 4;
#pragma unroll
    for (int nf = 0; nf < 6; ++nf) {
      const int col = nh * 96 + nf * 16 + l15;
#pragma unroll
      for (int r = 0; r < 4; ++r)
        xp[(row0 + r) * G_DIM + col] = (_Float16)(acc[m][nf][r] + bv[nf]);
    }
  }
}

// ---------------------------------------------------------------------------
// Kernel B: GRU recurrence, ONE barrier per step. 512 blocks x 1 row,
// 128 threads (2 waves). Thread = GRU unit j, owns FULL K=128 for its 3
// gate rows: w0/w1/w2[64] half2 = 192 weight VGPRs (static-indexed, no
// spill; 4 waves/CU = 1/SIMD so high VGPR costs nothing). Per step:
//   [prefetch xp(s+1)] [NLL(s-2)] [shfl-reduce decode(s-1)]
//   phase A: 16 broadcast b128 reads of h + 192 v_pk_fma_f16 -> full preacts
//   phase B: gate math in-thread -> hnew; ds_write_b16 to h2u[(s+1)&1]
//   BAR_LDS (single barrier; h double-buffered; vmcnt never drained)
// ---------------------------------------------------------------------------
__global__ __launch_bounds__(128, 1) void k_rec(
    const _Float16* __restrict__ xp, const float* __restrict__ gt,
    const float* __restrict__ Whh, const float* __restrict__ bhh,
    const float* __restrict__ Wdec, const float* __restrict__ bdec,
    float* __restrict__ ws_h, float* __restrict__ nll_part,
    int t0, int t1, int first) {
  __shared__ __align__(16) unsigned h2u[2][H_DIM / 2];  // double-buffered f16 h
  __shared__ float dw[2][2];                            // decode partial ring

  const int tid = threadIdx.x;   // unit j
  const int lane = tid & 63;
  const int wv = tid >> 6;
  const int row = blockIdx.x;

  // ---- one-time: full-K weight rows for unit tid, f16-packed ----
  half2_t w0[64], w1[64], w2[64];
  {
    const float4* p0 = (const float4*)(Whh + (size_t)tid * H_DIM);
    const float4* p1 = (const float4*)(Whh + (size_t)(H_DIM + tid) * H_DIM);
    const float4* p2 = (const float4*)(Whh + (size_t)(2 * H_DIM + tid) * H_DIM);
#pragma unroll
    for (int c = 0; c < 32; ++c) {
      float4 v;
      v = p0[c];
      w0[2 * c]     = (half2_t){(_Float16)v.x, (_Float16)v.y};
      w0[2 * c + 1] = (half2_t){(_Float16)v.z, (_Float16)v.w};
      v = p1[c];
      w1[2 * c]     = (half2_t){(_Float16)v.x, (_Float16)v.y};
      w1[2 * c + 1] = (half2_t){(_Float16)v.z, (_Float16)v.w};
      v = p2[c];
      w2[2 * c]     = (half2_t){(_Float16)v.x, (_Float16)v.y};
      w2[2 * c + 1] = (half2_t){(_Float16)v.z, (_Float16)v.w};
    }
  }
  const float bhn = bhh[2 * H_DIM + tid];
  const float wdj = Wdec[tid];
  const float bd0 = bdec[0];

  float h_old = first ? 0.f : ws_h[(size_t)row * H_DIM + tid];
  ((_Float16*)h2u[t0 & 1])[tid] = (_Float16)h_old;

  // first step's xp
  _Float16 xr_c, xz_c, xn_c;
  {
    const size_t b = (size_t)row * G_DIM;
    xr_c = xp[b + tid];
    xz_c = xp[b + H_DIM + tid];
    xn_c = xp[b + 2 * H_DIM + tid];
  }
  float nll0 = 0.f, g_old = 0.f, g_mid = 0.f, pv = 0.f;
  __syncthreads();

#pragma unroll 1
  for (int s = t0; s < t1; ++s) {
    // prefetch next step's xp (consumed after next barrier; vmcnt in flight)
    _Float16 xr_n = (_Float16)0.f, xz_n = (_Float16)0.f, xn_n = (_Float16)0.f;
    if (s + 1 < t1) {
      const size_t b = ((size_t)(s + 1 - t0) * B_DIM + row) * G_DIM;
      xr_n = xp[b + tid];
      xz_n = xp[b + H_DIM + tid];
      xn_n = xp[b + 2 * H_DIM + tid];
    }
    // NLL for step s-2 (dw slot (s-2)&1 == s&1, written at top of s-1)
    if (tid == 0) {
      if (s >= t0 + 2) {
        const float v = dw[s & 1][0] + dw[s & 1][1];
        const float C = 1.f / (1.f + __expf(-(v + bd0)));
        nll0 -= g_old * __logf(C + 1e-4f) +
                (1.f - g_old) * __logf(1.f - C + 1e-4f);
      }
      g_old = g_mid;
      g_mid = gt[(size_t)(s + 1) * B_DIM + row];
    }
    // decode shfl-reduce for step s-1's hnew (hides under phase A)
    if (s > t0) {
      float v = pv;
#pragma unroll
      for (int off = 32; off; off >>= 1) v += __shfl_down(v, off);
      if (lane == 0) dw[(s - 1) & 1][wv] = v;
    }

    // ---- phase A: full-K matvec in-thread, h broadcast from LDS ----
    half2_t a0 = (half2_t){0, 0}, a1 = (half2_t){0, 0}, a2 = (half2_t){0, 0};
    const uint4* hb = (const uint4*)h2u[s & 1];
#pragma unroll
    for (int c = 0; c < 16; ++c) {
      const uint4 hq = hb[c];  // wave-uniform address -> broadcast
      const half2_t h0 = __builtin_bit_cast(half2_t, hq.x);
      const half2_t h1 = __builtin_bit_cast(half2_t, hq.y);
      const half2_t h2 = __builtin_bit_cast(half2_t, hq.z);
      const half2_t h3 = __builtin_bit_cast(half2_t, hq.w);
      a0 = h0 * w0[4 * c] + a0;     a1 = h0 * w1[4 * c] + a1;     a2 = h0 * w2[4 * c] + a2;
      a0 = h1 * w0[4 * c + 1] + a0; a1 = h1 * w1[4 * c + 1] + a1; a2 = h1 * w2[4 * c + 1] + a2;
      a0 = h2 * w0[4 * c + 2] + a0; a1 = h2 * w1[4 * c + 2] + a1; a2 = h2 * w2[4 * c + 2] + a2;
      a0 = h3 * w0[4 * c + 3] + a0; a1 = h3 * w1[4 * c + 3] + a1; a2 = h3 * w2[4 * c + 3] + a2;
    }

    // ---- phase B: gate math, same thread (no exchange) ----
    const float rp = (float)a0.x + (float)a0.y + (float)xr_c;  // bhh_r in xp
    const float zp = (float)a1.x + (float)a1.y + (float)xz_c;
    const float hn = (float)a2.x + (float)a2.y + bhn;
    const float r_ = 1.f / (1.f + __expf(-rp));
    const float z_ = 1.f / (1.f + __expf(-zp));
    const float e2 = __expf(2.f * ((float)xn_c + r_ * hn));
    const float n_ = 1.f - 2.f / (e2 + 1.f);
    const float hnew = (1.f - z_) * n_ + z_ * h_old;
    h_old = hnew;
    ((_Float16*)h2u[(s + 1) & 1])[tid] = (_Float16)hnew;
    pv = hnew * wdj;
    xr_c = xr_n; xz_c = xz_n; xn_c = xn_n;
    BAR_LDS();  // the ONE barrier: h(s+1) published
  }

  // ---- epilogue: flush the 2-deep NLL pipeline ----
  {
    float v = pv;  // decode for step t1-1
#pragma unroll
    for (int off = 32; off; off >>= 1) v += __shfl_down(v, off);
    if (lane == 0) dw[(t1 - 1) & 1][wv] = v;
    if (tid == 0 && t1 - t0 >= 2) {  // NLL(t1-2): slot (t1-2)&1 == t1&1
      const float vv = dw[t1 & 1][0] + dw[t1 & 1][1];
      const float C = 1.f / (1.f + __expf(-(vv + bd0)));
      nll0 -= g_old * __logf(C + 1e-4f) +
              (1.f - g_old) * __logf(1.f - C + 1e-4f);
    }
    BAR_LDS();
    if (tid == 0) {  // NLL(t1-1), gt[t1] = g_mid
      const float vv = dw[(t1 - 1) & 1][0] + dw[(t1 - 1) & 1][1];
      const float C = 1.f / (1.f + __expf(-(vv + bd0)));
      nll0 -= g_mid * __logf(C + 1e-4f) +
              (1.f - g_mid) * __logf(1.f - C + 1e-4f);
      nll_part[row] = first ? nll0 : (nll_part[row] + nll0);
    }
  }
  ws_h[(size_t)row * H_DIM + tid] = h_old;
}

// ---------------------------------------------------------------------------
__global__ __launch_bounds__(512) void k_fin(const float* __restrict__ nll_part,
                                             float* __restrict__ out) {
  __shared__ float red[8];
  const int tid = threadIdx.x;
  float v = nll_part[tid];
#pragma unroll
  for (int off = 32; off; off >>= 1) v += __shfl_down(v, off);
  if ((tid & 63) == 0) red[tid >> 6] = v;
  __syncthreads();
  if (tid == 0) {
    float s = 0.f;
#pragma unroll
    for (int i = 0; i < 8; ++i) s += red[i];
    out[0] = s * (1.f / (512.f * 512.f));
  }
}

// ---------------------------------------------------------------------------
extern "C" void kernel_launch(void* const* d_in, const int* in_sizes, int n_in,
                              void* d_out, int out_size, void* d_ws,
                              size_t ws_size, hipStream_t stream) {
  const float* x    = (const float*)d_in[0];
  const float* gt   = (const float*)d_in[1];
  const float* Wih  = (const float*)d_in[2];
  const float* Whh  = (const float*)d_in[3];
  const float* bih  = (const float*)d_in[4];
  const float* bhh  = (const float*)d_in[5];
  const float* Wdec = (const float*)d_in[6];
  const float* bdec = (const float*)d_in[7];

  // ws layout: [0,2KB) nll_part[512]; [4KB,260KB) h state; then xp chunk
  float* nll_part = (float*)d_ws;
  float* ws_h = (float*)((char*)d_ws + 4096);
  const size_t xp_off = 4096 + (size_t)B_DIM * H_DIM * 4;  // 266240
  _Float16* xp = (_Float16*)((char*)d_ws + xp_off);

  const size_t chunk_bytes = (size_t)B_DIM * G_DIM * 2;  // fp16 per timestep
  size_t avail = ws_size > xp_off ? ws_size - xp_off : 0;
  int Tc = (int)(avail / chunk_bytes);
  if (Tc > 128) Tc = 128;      // xp chunk <=50 MB, L3-resident
  if (Tc < 1) Tc = 1;

  for (int t0 = 0; t0 < STEPS; t0 += Tc) {
    int t1 = t0 + Tc;
    if (t1 > STEPS) t1 = STEPS;
    const int nt = t1 - t0;
    k_xproj<<<dim3(nt * 4), dim3(512), 0, stream>>>(
        x + (size_t)t0 * B_DIM * I_DIM, Wih, bih, bhh, xp);
    k_rec<<<dim3(512), dim3(128), 0, stream>>>(
        xp, gt, Whh, bhh, Wdec, bdec, ws_h, nll_part, t0, t1, t0 == 0 ? 1 : 0);
  }
  k_fin<<<dim3(1), dim3(512), 0, stream>>>(nll_part, (float*)d_out);
}